// Round 18
// baseline (588.190 us; speedup 1.0000x reference)
//
#include <hip/hip_runtime.h>
#include <math.h>

#define H 8
#define KK 2048
#define DD 64
#define HIDN 1024
#define BB 8192
#define TWO_D 128
#define OO 128

// ws float-element offsets
// [0, 1048576): staged codebook fragments — hi-only bf16, chunk-major:
//   tile T stored at slot (T&15)*8 + (T>>4); chunk c sub-slot kg = tile kg*16+c (k = kg*256+c*16+lane)
#define WS_CSQ   1048576
#define WS_ZSQ   1064960
#define WS_IDX   1130496
#define WS_AVGP  1196032
#define WS_HIST  1212416
#define WS_ACC   1228800
#define WS_ZERO_BYTES ((16384 + 16384 + 4) * 4)

#define OUT_ZQ 0
#define OUT_IDX 8388608
#define OUT_COMMIT 8454144
#define OUT_CBL 8454145
#define OUT_ENT 8454146
#define OUT_ORTHO 8454147
#define OUT_ZH 8454148
#define W2P_OFF 3145728

typedef __attribute__((ext_vector_type(8))) short bf16x8;
typedef __attribute__((ext_vector_type(4))) float f32x4;

__device__ inline unsigned short bf16_rne(float x) {
    union { float f; unsigned u; } c; c.f = x;
    unsigned r = c.u + 0x7FFFu + ((c.u >> 16) & 1u);
    return (unsigned short)(r >> 16);
}
__device__ inline float bf16_f32(unsigned short h) {
    union { unsigned u; float f; } c; c.u = ((unsigned)h) << 16;
    return c.f;
}
__device__ inline void split3(float x, short* hh, short* mm, short* ll) {
    unsigned short h_ = bf16_rne(x);
    float r1 = x - bf16_f32(h_);
    unsigned short m_ = bf16_rne(r1);
    float r2 = r1 - bf16_f32(m_);
    unsigned short l_ = bf16_rne(r2);
    *hh = (short)h_; *mm = (short)m_; *ll = (short)l_;
}

__device__ inline void gload_lds16(const void* g, void* l) {
    __builtin_amdgcn_global_load_lds(
        (const __attribute__((address_space(1))) unsigned int*)g,
        (__attribute__((address_space(3))) unsigned int*)l, 16, 0, 0);
}

// ---------------- k_pre_all: w1 pack (blocks 0..255) | w2 pack (256..263) | codebook pack (264..327) ----------------
__global__ __launch_bounds__(256) void k_pre_all(const float* __restrict__ w1, const float* __restrict__ w2,
                                                 const float* __restrict__ cb, float* outp,
                                                 float* __restrict__ ws) {
    int bid = blockIdx.x;
    int t = threadIdx.x;
    int l = t & 63, w = t >> 6;
    int lb = l & 15, lg = l >> 4;
    if (bid < 256) {
        short* w1p = (short*)outp;
        int h = bid >> 5, kc = bid & 31;
#pragma unroll
        for (int oi = 0; oi < 2; ++oi) {
            int ot = w + oi * 4;
            union { short e[8]; bf16x8 v; } uh, um, ul;
#pragma unroll
            for (int j = 0; j < 8; ++j) {
                float x = w1[(size_t)(h * HIDN + kc * 32 + lg * 8 + j) * TWO_D + ot * 16 + lb];
                split3(x, &uh.e[j], &um.e[j], &ul.e[j]);
            }
            size_t base = (((size_t)(h * 32 + kc) * 8 + ot) * 3) * 512 + l * 8;
            *(bf16x8*)(w1p + base) = uh.v;
            *(bf16x8*)(w1p + base + 512) = um.v;
            *(bf16x8*)(w1p + base + 1024) = ul.v;
        }
    } else if (bid < 264) {
        short* w2p = (short*)outp + W2P_OFF;
        int h = bid - 256;
#pragma unroll
        for (int i = 0; i < 4; ++i) {
            int fr = w * 4 + i;
            int dt = fr >> 2, oc = fr & 3;
            union { short e[8]; bf16x8 v; } uh, um, ul;
#pragma unroll
            for (int j = 0; j < 8; ++j) {
                float x = w2[(size_t)(h * TWO_D + oc * 32 + lg * 8 + j) * DD + dt * 16 + lb];
                split3(x, &uh.e[j], &um.e[j], &ul.e[j]);
            }
            size_t base = (((size_t)(h * 4 + dt) * 4 + oc) * 3) * 512 + l * 8;
            *(bf16x8*)(w2p + base) = uh.v;
            *(bf16x8*)(w2p + base + 512) = um.v;
            *(bf16x8*)(w2p + base + 1024) = ul.v;
        }
    } else {
        int pb = bid - 264;
        int h = pb >> 3, kb = pb & 7;
        short* stg = (short*)ws;
#pragma unroll
        for (int p = 0; p < 4; ++p) {
            int T = kb * 16 + p * 4 + (t >> 6);
            int k = T * 16 + lb;
            const float* row = cb + (size_t)(h * KK + k) * DD;
            float4 a0 = *(const float4*)(row + ((t >> 4) & 3) * 8);
            float4 a1 = *(const float4*)(row + ((t >> 4) & 3) * 8 + 4);
            float4 c0 = *(const float4*)(row + 32 + ((t >> 4) & 3) * 8);
            float4 c1 = *(const float4*)(row + 32 + ((t >> 4) & 3) * 8 + 4);
            float v0[8] = {a0.x, a0.y, a0.z, a0.w, a1.x, a1.y, a1.z, a1.w};
            float v1[8] = {c0.x, c0.y, c0.z, c0.w, c1.x, c1.y, c1.z, c1.w};
            union { short e[8]; bf16x8 v; } h0, h1;
            float s = 0.f;
#pragma unroll
            for (int j = 0; j < 8; ++j) {
                float x = v0[j];
                s = fmaf(x, x, s);
                h0.e[j] = (short)bf16_rne(x);
                float y = v1[j];
                s = fmaf(y, y, s);
                h1.e[j] = (short)bf16_rne(y);
            }
            int off = (T & 15) * 8 + (T >> 4);
            size_t base = ((size_t)(h * 128 + off)) * 1024 + (t & 63) * 8;
            *(bf16x8*)(stg + base) = h0.v;
            *(bf16x8*)(stg + base + 512) = h1.v;
            s += __shfl_xor(s, 16);
            s += __shfl_xor(s, 32);
            if (((t >> 4) & 3) == 0) ws[WS_CSQ + h * KK + k] = s;
        }
    }
}

// ---------------- k1: MFMA split-3 MLP, 256 rows/block (staging quartered vs r15) ----------------
// 1024 thr = 16 waves = 8 rowgroups x 2 colgroups; wave: 32 rows (mf 0,1) x 64 cols (ot 0..3).
__global__ __launch_bounds__(1024) void k1(const float* __restrict__ z, const float* __restrict__ b1,
                                           const float* __restrict__ b2, const float* __restrict__ lng,
                                           const float* __restrict__ lnb, float* out,
                                           float* __restrict__ ws) {
    __shared__ char SM[69632];  // staging [0,49152); epi: h1H [256][68] f32 @0; zhL reuses @0
    int t = threadIdx.x;
    int h = blockIdx.y;
    int b0 = blockIdx.x * 256;
    int w = t >> 6, l = t & 63;
    int rg = w >> 1, wc = w & 1;
    int lb = l & 15, lg = l >> 4;

    const short* w2p = (const short*)out + W2P_OFF;
    const char* w1h = (const char*)out + (size_t)h * (32 * 24576);
    const float* zrow0 = z + (size_t)(b0 + rg * 32 + lb) * HIDN + lg * 8;
    const float* zrow1 = zrow0 + 16 * HIDN;

    // stage chunk: 24KB = 16KB (all 16 waves) + 8KB (waves 0..7)
    {
        char* d0 = SM + (t >> 6) * 1024;
        const char* gb = w1h;
        gload_lds16(gb + t * 16, d0 + l * 16 - l * 16 + (l * 16));  // placeholder removed below
    }
    // (real prologue below)
    // --- prologue: stage(0), stage(1), z(0), full drain ---
    {
        char* buf0 = SM;
        char* buf1 = SM + 24576;
        const char* g0 = w1h;
        const char* g1 = w1h + 24576;
        // stage(0)
        gload_lds16(g0 + t * 16, buf0 + (t >> 6) * 1024);
        if (w < 8) gload_lds16(g0 + 16384 + t * 16, buf0 + 16384 + (t >> 6) * 1024);
        // stage(1)
        gload_lds16(g1 + t * 16, buf1 + (t >> 6) * 1024);
        if (w < 8) gload_lds16(g1 + 16384 + t * 16, buf1 + 16384 + (t >> 6) * 1024);
    }
    float4 zA0 = *(const float4*)(zrow0);
    float4 zB0 = *(const float4*)(zrow0 + 4);
    float4 zA1 = *(const float4*)(zrow1);
    float4 zB1 = *(const float4*)(zrow1 + 4);
    __syncthreads();

    f32x4 acc[2][4];
#pragma unroll
    for (int i = 0; i < 2; ++i)
#pragma unroll
        for (int j = 0; j < 4; ++j) acc[i][j] = (f32x4){0.f, 0.f, 0.f, 0.f};

#pragma unroll
    for (int c = 0; c < 32; ++c) {
        if (c > 0) {
            if (c < 31) {
                if (w < 8) asm volatile("s_waitcnt vmcnt(2)" ::: "memory");
                else       asm volatile("s_waitcnt vmcnt(1)" ::: "memory");
            } else {
                asm volatile("s_waitcnt vmcnt(0)" ::: "memory");
            }
            __builtin_amdgcn_sched_barrier(0);
            __builtin_amdgcn_s_barrier();
            __builtin_amdgcn_sched_barrier(0);
        }
        {
            // B-frags for both row-frags
            bf16x8 bh[2], bm[2], bl[2];
#pragma unroll
            for (int mf = 0; mf < 2; ++mf) {
                float zc[8];
                if (mf == 0) { zc[0]=zA0.x; zc[1]=zA0.y; zc[2]=zA0.z; zc[3]=zA0.w; zc[4]=zB0.x; zc[5]=zB0.y; zc[6]=zB0.z; zc[7]=zB0.w; }
                else         { zc[0]=zA1.x; zc[1]=zA1.y; zc[2]=zA1.z; zc[3]=zA1.w; zc[4]=zB1.x; zc[5]=zB1.y; zc[6]=zB1.z; zc[7]=zB1.w; }
                union { short e[8]; bf16x8 v; } uh, um, ul;
#pragma unroll
                for (int j = 0; j < 8; ++j) split3(zc[j], &uh.e[j], &um.e[j], &ul.e[j]);
                bh[mf] = uh.v; bm[mf] = um.v; bl[mf] = ul.v;
            }
            const char* bp = SM + (c & 1) * 24576;
#pragma unroll
            for (int ot = 0; ot < 4; ++ot) {
                const char* fb = bp + (wc * 4 + ot) * 3072 + l * 16;
                bf16x8 ah = *(const bf16x8*)(fb);
                bf16x8 am = *(const bf16x8*)(fb + 1024);
                bf16x8 al = *(const bf16x8*)(fb + 2048);
#pragma unroll
                for (int mf = 0; mf < 2; ++mf) {
                    f32x4 cc = acc[mf][ot];
                    cc = __builtin_amdgcn_mfma_f32_16x16x32_bf16(ah, bh[mf], cc, 0, 0, 0);
                    cc = __builtin_amdgcn_mfma_f32_16x16x32_bf16(ah, bm[mf], cc, 0, 0, 0);
                    cc = __builtin_amdgcn_mfma_f32_16x16x32_bf16(am, bh[mf], cc, 0, 0, 0);
                    cc = __builtin_amdgcn_mfma_f32_16x16x32_bf16(ah, bl[mf], cc, 0, 0, 0);
                    cc = __builtin_amdgcn_mfma_f32_16x16x32_bf16(al, bh[mf], cc, 0, 0, 0);
                    cc = __builtin_amdgcn_mfma_f32_16x16x32_bf16(am, bm[mf], cc, 0, 0, 0);
                    acc[mf][ot] = cc;
                }
            }
        }
        __builtin_amdgcn_sched_barrier(0);
        __builtin_amdgcn_s_barrier();
        __builtin_amdgcn_sched_barrier(0);
        if (c < 31) {
            zA0 = *(const float4*)(zrow0 + (c + 1) * 32);
            zB0 = *(const float4*)(zrow0 + (c + 1) * 32 + 4);
            zA1 = *(const float4*)(zrow1 + (c + 1) * 32);
            zB1 = *(const float4*)(zrow1 + (c + 1) * 32 + 4);
        }
        if (c + 2 < 32) {
            char* buf = SM + (c & 1) * 24576;
            const char* gb = w1h + (size_t)(c + 2) * 24576;
            gload_lds16(gb + t * 16, buf + (t >> 6) * 1024);
            if (w < 8) gload_lds16(gb + 16384 + t * 16, buf + 16384 + (t >> 6) * 1024);
        }
    }
    __syncthreads();   // staging dead

    float* h1H = (float*)SM;   // [256][68] per col-half

    f32x4 a2[2][2];
#pragma unroll
    for (int i = 0; i < 2; ++i)
#pragma unroll
        for (int j = 0; j < 2; ++j) a2[i][j] = (f32x4){0.f, 0.f, 0.f, 0.f};

#pragma unroll
    for (int half = 0; half < 2; ++half) {
        __syncthreads();   // protect previous half's reads
        if (wc == half) {
#pragma unroll
            for (int ot = 0; ot < 4; ++ot)
#pragma unroll
                for (int mf = 0; mf < 2; ++mf)
#pragma unroll
                    for (int r = 0; r < 4; ++r) {
                        int og = half * 64 + ot * 16 + lg * 4 + r;
                        float x = acc[mf][ot][r] + b1[h * TWO_D + og];
                        float gl = 0.5f * x * (1.0f + erff(x * 0.70710678118654752f));
                        h1H[(rg * 32 + mf * 16 + lb) * 68 + ot * 16 + lg * 4 + r] = gl;
                    }
        }
        __syncthreads();
#pragma unroll
        for (int oci = 0; oci < 2; ++oci) {
            int oc = half * 2 + oci;
#pragma unroll
            for (int mf = 0; mf < 2; ++mf) {
                const float* hr = h1H + (rg * 32 + mf * 16 + lb) * 68 + oci * 32 + lg * 8;
                union { short e[8]; bf16x8 v; } uh, um, ul;
#pragma unroll
                for (int j = 0; j < 8; ++j) split3(hr[j], &uh.e[j], &um.e[j], &ul.e[j]);
                bf16x8 bh = uh.v, bm = um.v, blo = ul.v;
#pragma unroll
                for (int dti = 0; dti < 2; ++dti) {
                    int dt = wc * 2 + dti;
                    const short* fb = w2p + (((size_t)(h * 4 + dt) * 4 + oc) * 3) * 512 + l * 8;
                    bf16x8 ah = *(const bf16x8*)(fb);
                    bf16x8 am = *(const bf16x8*)(fb + 512);
                    bf16x8 al = *(const bf16x8*)(fb + 1024);
                    f32x4 cc = a2[mf][dti];
                    cc = __builtin_amdgcn_mfma_f32_16x16x32_bf16(ah, bh, cc, 0, 0, 0);
                    cc = __builtin_amdgcn_mfma_f32_16x16x32_bf16(ah, bm, cc, 0, 0, 0);
                    cc = __builtin_amdgcn_mfma_f32_16x16x32_bf16(am, bh, cc, 0, 0, 0);
                    cc = __builtin_amdgcn_mfma_f32_16x16x32_bf16(ah, blo, cc, 0, 0, 0);
                    cc = __builtin_amdgcn_mfma_f32_16x16x32_bf16(al, bh, cc, 0, 0, 0);
                    cc = __builtin_amdgcn_mfma_f32_16x16x32_bf16(am, bm, cc, 0, 0, 0);
                    a2[mf][dti] = cc;
                }
            }
        }
    }
    __syncthreads();   // h1H dead; reuse as zhL

    float* zhL = (float*)SM;   // [256][68]
#pragma unroll
    for (int mf = 0; mf < 2; ++mf)
#pragma unroll
        for (int dti = 0; dti < 2; ++dti) {
            int dt = wc * 2 + dti;
#pragma unroll
            for (int r = 0; r < 4; ++r) {
                int d = dt * 16 + lg * 4 + r;
                zhL[(rg * 32 + mf * 16 + lb) * 68 + d] = a2[mf][dti][r] + b2[h * DD + d];
            }
        }
    __syncthreads();

    // LayerNorm: 4 threads/row, 16 d's each; 1024 thr -> 256 rows
    {
        int row = t >> 2, c0 = (t & 3) * 16;
        const float* zr = zhL + row * 68 + c0;
        float v[16];
#pragma unroll
        for (int j = 0; j < 16; ++j) v[j] = zr[j];
        float s = 0.f;
#pragma unroll
        for (int j = 0; j < 16; ++j) s += v[j];
        s += __shfl_xor(s, 1); s += __shfl_xor(s, 2);
        float mu = s * (1.0f / 64.0f);
        float vv = 0.f;
#pragma unroll
        for (int j = 0; j < 16; ++j) { float d = v[j] - mu; vv = fmaf(d, d, vv); }
        vv += __shfl_xor(vv, 1); vv += __shfl_xor(vv, 2);
        float rstd = 1.0f / sqrtf(vv * (1.0f / 64.0f) + 1e-5f);
        float zn[16]; float ss = 0.f;
#pragma unroll
        for (int j = 0; j < 16; ++j) {
            float x = (v[j] - mu) * rstd * lng[h * DD + c0 + j] + lnb[h * DD + c0 + j];
            zn[j] = x; ss = fmaf(x, x, ss);
        }
        ss += __shfl_xor(ss, 1); ss += __shfl_xor(ss, 2);
        int brow = b0 + row;
        if ((t & 3) == 0) ws[WS_ZSQ + brow * H + h] = ss;
#pragma unroll
        for (int q = 0; q < 4; ++q) {
            float4 sv = {zn[q * 4 + 0], zn[q * 4 + 1], zn[q * 4 + 2], zn[q * 4 + 3]};
            *(float4*)(out + OUT_ZH + (size_t)(brow * H + h) * DD + c0 + q * 4) = sv;
        }
    }
}

// ---------------- k2: hi-only MFMA, 1024-thr / 16-wave blocks (r17, k = kg*256+ai*16+lb) ----------------
#define MARGIN 0.10f
__device__ inline void stage16k(const char* gsrc, short* lbuf, int t) {
    char* lb_ = (char*)lbuf + (t >> 6) * 1024;
    const char* gb = gsrc + t * 16;
    gload_lds16(gb, lb_);
}
__global__ __launch_bounds__(1024) void k2(const float* __restrict__ cb,
                                           float* __restrict__ out, float* __restrict__ ws) {
    __shared__ short bufs[3][8192];
    __shared__ float zt[32][68];
    __shared__ float redM[8][32], redS[8][32], redE[8][32];
    __shared__ int   redK[8][32];
    __shared__ float MbL[32], SbL[32];
    __shared__ float zsqL[32];

    int t = threadIdx.x;
    int h = blockIdx.y;
    int b0 = blockIdx.x * 32;
    int w = t >> 6, l = t & 63;
    int rg = w >> 3, kg = w & 7;
    int lb = l & 15, lg = l >> 4;
    int rmy = rg * 16 + lb;

    const char* stgbase = (const char*)ws + (size_t)h * 262144;

    stage16k(stgbase, bufs[0], t);
    stage16k(stgbase + 16384, bufs[1], t);
    stage16k(stgbase + 32768, bufs[2], t);
#pragma unroll
    for (int i = 0; i < 2; ++i) {
        int q = t + i * 1024;
        int r = q >> 6, d = q & 63;
        zt[r][d] = out[OUT_ZH + (size_t)((b0 + r) * H + h) * DD + d];
    }
    if (t < 32) zsqL[t] = ws[WS_ZSQ + (b0 + t) * H + h];
    __syncthreads();

    bf16x8 bh[2], blo[2];
#pragma unroll
    for (int s = 0; s < 2; ++s) {
        const float* zr = &zt[rmy][s * 32 + lg * 8];
        union { short e[8]; bf16x8 v; } uh, ul;
#pragma unroll
        for (int j = 0; j < 8; ++j) {
            float x = zr[j];
            unsigned short hb = bf16_rne(x);
            uh.e[j] = (short)hb;
            ul.e[j] = (short)bf16_rne(x - bf16_f32(hb));
        }
        bh[s] = uh.v; blo[s] = ul.v;
    }

    f32x4 acc[16];
#pragma unroll
    for (int a = 0; a < 16; ++a) acc[a] = (f32x4){0.f, 0.f, 0.f, 0.f};

#pragma unroll
    for (int c = 0; c < 16; ++c) {
        if (c > 0) {
            if (c <= 13)      asm volatile("s_waitcnt vmcnt(2)" ::: "memory");
            else if (c == 14) asm volatile("s_waitcnt vmcnt(1)" ::: "memory");
            else              asm volatile("s_waitcnt vmcnt(0)" ::: "memory");
            __builtin_amdgcn_sched_barrier(0);
            __builtin_amdgcn_s_barrier();
            __builtin_amdgcn_sched_barrier(0);
        }
        {
            const short* fb = bufs[c % 3] + kg * 1024 + l * 8;
            bf16x8 C0 = *(const bf16x8*)(fb);
            bf16x8 C1 = *(const bf16x8*)(fb + 512);
            f32x4 cc = acc[c];
            cc = __builtin_amdgcn_mfma_f32_16x16x32_bf16(bh[0], C0, cc, 0, 0, 0);
            cc = __builtin_amdgcn_mfma_f32_16x16x32_bf16(blo[0], C0, cc, 0, 0, 0);
            cc = __builtin_amdgcn_mfma_f32_16x16x32_bf16(bh[1], C1, cc, 0, 0, 0);
            cc = __builtin_amdgcn_mfma_f32_16x16x32_bf16(blo[1], C1, cc, 0, 0, 0);
            acc[c] = cc;
        }
        if (c < 15) {
            __builtin_amdgcn_sched_barrier(0);
            __builtin_amdgcn_s_barrier();
            __builtin_amdgcn_sched_barrier(0);
            if (c + 3 < 16)
                stage16k(stgbase + (size_t)(c + 3) * 16384, bufs[c % 3], t);
        }
    }

    float zsqv[4];
#pragma unroll
    for (int r = 0; r < 4; ++r) zsqv[r] = zsqL[rg * 16 + lg * 4 + r];
    float mn[4] = {3.4e38f, 3.4e38f, 3.4e38f, 3.4e38f};
#pragma unroll
    for (int ai = 0; ai < 16; ++ai) {
        float cs = ws[WS_CSQ + h * KK + kg * 256 + ai * 16 + lb];
        f32x4 a = acc[ai];
        f32x4 d;
#pragma unroll
        for (int r = 0; r < 4; ++r) {
            float dv = (zsqv[r] + cs) - 2.f * a[r];
            d[r] = dv;
            mn[r] = fminf(mn[r], dv);
        }
        acc[ai] = d;
    }
#pragma unroll
    for (int off = 1; off < 16; off <<= 1)
#pragma unroll
        for (int r = 0; r < 4; ++r) mn[r] = fminf(mn[r], __shfl_xor(mn[r], off));
    if (lb == 0)
#pragma unroll
        for (int r = 0; r < 4; ++r) redM[kg][rg * 16 + lg * 4 + r] = mn[r];
    __syncthreads();
    if (t < 32) {
        float m = redM[0][t];
#pragma unroll
        for (int g = 1; g < 8; ++g) m = fminf(m, redM[g][t]);
        MbL[t] = m;
    }
    __syncthreads();
    float Mb[4];
#pragma unroll
    for (int r = 0; r < 4; ++r) Mb[r] = MbL[rg * 16 + lg * 4 + r];

    float S[4] = {0.f, 0.f, 0.f, 0.f};
    unsigned mk0 = 0, mk1 = 0, mk2 = 0, mk3 = 0;
#pragma unroll
    for (int ai = 0; ai < 16; ++ai) {
        f32x4 d = acc[ai];
        f32x4 e;
#pragma unroll
        for (int r = 0; r < 4; ++r) {
            float dv = d[r];
            float ev = __expf(Mb[r] - dv);
            S[r] += ev;
            e[r] = ev;
            bool cand = dv <= Mb[r] + MARGIN;
            if (r == 0) mk0 |= cand ? (1u << ai) : 0u;
            if (r == 1) mk1 |= cand ? (1u << ai) : 0u;
            if (r == 2) mk2 |= cand ? (1u << ai) : 0u;
            if (r == 3) mk3 |= cand ? (1u << ai) : 0u;
        }
        acc[ai] = e;
    }
#pragma unroll
    for (int off = 1; off < 16; off <<= 1)
#pragma unroll
        for (int r = 0; r < 4; ++r) S[r] += __shfl_xor(S[r], off);
    if (lb == 0)
#pragma unroll
        for (int r = 0; r < 4; ++r) redS[kg][rg * 16 + lg * 4 + r] = S[r];

    float eB[4] = {3.4e38f, 3.4e38f, 3.4e38f, 3.4e38f};
    int kB[4] = {0x7FFFFFFF, 0x7FFFFFFF, 0x7FFFFFFF, 0x7FFFFFFF};
#pragma unroll
    for (int r = 0; r < 4; ++r) {
        unsigned m = (r == 0) ? mk0 : (r == 1) ? mk1 : (r == 2) ? mk2 : mk3;
        const float* zr0 = &zt[rg * 16 + lg * 4 + r][0];
        float eBest = 3.4e38f; int kBest = 0x7FFFFFFF;
        while (m) {
            int ai = (int)__ffs(m) - 1;
            m &= m - 1;
            int k = kg * 256 + ai * 16 + lb;
            const float4* crow = (const float4*)(cb + (size_t)(h * KK + k) * DD);
            float s = 0.f;
#pragma unroll 1
            for (int q = 0; q < 16; ++q) {
                float4 cv = crow[q];
                s = fmaf(zr0[q * 4 + 0], cv.x, s);
                s = fmaf(zr0[q * 4 + 1], cv.y, s);
                s = fmaf(zr0[q * 4 + 2], cv.z, s);
                s = fmaf(zr0[q * 4 + 3], cv.w, s);
            }
            float ex = (zsqv[r] + ws[WS_CSQ + h * KK + k]) - 2.f * s;
            if (ex < eBest || (ex == eBest && k < kBest)) { eBest = ex; kBest = k; }
        }
        eB[r] = eBest; kB[r] = kBest;
    }
#pragma unroll
    for (int off = 1; off < 16; off <<= 1)
#pragma unroll
        for (int r = 0; r < 4; ++r) {
            float oe = __shfl_xor(eB[r], off);
            int ok = __shfl_xor(kB[r], off);
            if (oe < eB[r] || (oe == eB[r] && ok < kB[r])) { eB[r] = oe; kB[r] = ok; }
        }
    if (lb == 0)
#pragma unroll
        for (int r = 0; r < 4; ++r) {
            redE[kg][rg * 16 + lg * 4 + r] = eB[r];
            redK[kg][rg * 16 + lg * 4 + r] = kB[r];
        }
    __syncthreads();
    if (t < 32) {
        float Sv = redS[0][t];
#pragma unroll
        for (int g = 1; g < 8; ++g) Sv += redS[g][t];
        SbL[t] = Sv;
        float e0 = redE[0][t]; int k0_ = redK[0][t];
#pragma unroll
        for (int g = 1; g < 8; ++g) {
            float oe = redE[g][t]; int ok = redK[g][t];
            if (oe < e0 || (oe == e0 && ok < k0_)) { e0 = oe; k0_ = ok; }
        }
        out[OUT_IDX + (b0 + t) * H + h] = (float)k0_;
        ((int*)ws)[WS_IDX + (b0 + t) * H + h] = k0_;
        atomicAdd(((unsigned*)ws) + WS_HIST + h * KK + k0_, 1u);
    }
    __syncthreads();
    float invS[4];
#pragma unroll
    for (int r = 0; r < 4; ++r) invS[r] = 1.0f / SbL[rg * 16 + lg * 4 + r];

#pragma unroll
    for (int ai = 0; ai < 16; ++ai) {
        f32x4 e = acc[ai];
        float v = e[0] * invS[0];
        v = fmaf(e[1], invS[1], v);
        v = fmaf(e[2], invS[2], v);
        v = fmaf(e[3], invS[3], v);
        v += __shfl_xor(v, 16);
        v += __shfl_xor(v, 32);
        if (lg == 0) atomicAdd(ws + WS_AVGP + h * KK + kg * 256 + ai * 16 + lb, v);
    }
}

// ---------------- k3: decode z_q and z_heads, z_q_st output, commit accum ----------------
__global__ __launch_bounds__(256, 2) void k3(const float* __restrict__ cb, const float* __restrict__ dw,
                                             const float* __restrict__ db, float* __restrict__ out,
                                             float* __restrict__ ws) {
    __shared__ float zqt[32][65];
    __shared__ float zht[32][65];
    __shared__ float dwt[64][128];
    __shared__ int idxs[32];
    __shared__ double redc[4];
    int t = threadIdx.x;
    int h = blockIdx.y;
    int b0 = blockIdx.x * 32;
    if (t < 32) idxs[t] = ((const int*)ws)[WS_IDX + (b0 + t) * H + h];
    __syncthreads();
#pragma unroll
    for (int p = 0; p < 8; ++p) {
        int q = t + 256 * p;
        int r = q >> 6, d = q & 63;
        zqt[r][d] = cb[(size_t)(h * KK + idxs[r]) * DD + d];
        zht[r][d] = out[OUT_ZH + (size_t)((b0 + r) * H + h) * DD + d];
    }
#pragma unroll
    for (int p = 0; p < 8; ++p) {
        int q = t + 256 * p;
        int r = q >> 5, c4 = q & 31;
        *(float4*)(&dwt[r][c4 * 4]) = *(const float4*)(dw + (size_t)(h * DD + r) * OO + c4 * 4);
    }
    __syncthreads();
    int rg = t >> 4, cg = t & 15;
    float aq[2][8], ap[2][8];
#pragma unroll
    for (int i = 0; i < 2; ++i)
#pragma unroll
        for (int j = 0; j < 8; ++j) { aq[i][j] = 0.f; ap[i][j] = 0.f; }
#pragma unroll 4
    for (int d = 0; d < 64; ++d) {
        float q0 = zqt[rg * 2][d], q1 = zqt[rg * 2 + 1][d];
        float p0 = zht[rg * 2][d], p1 = zht[rg * 2 + 1][d];
        float4 wa = *(const float4*)(&dwt[d][cg * 8]);
        float4 wb = *(const float4*)(&dwt[d][cg * 8 + 4]);
        float ww[8] = {wa.x, wa.y, wa.z, wa.w, wb.x, wb.y, wb.z, wb.w};
#pragma unroll
        for (int j = 0; j < 8; ++j) {
            aq[0][j] = fmaf(q0, ww[j], aq[0][j]);
            aq[1][j] = fmaf(q1, ww[j], aq[1][j]);
            ap[0][j] = fmaf(p0, ww[j], ap[0][j]);
            ap[1][j] = fmaf(p1, ww[j], ap[1][j]);
        }
    }
    float lsum = 0.f;
#pragma unroll
    for (int i = 0; i < 2; ++i) {
        float vq4[8];
#pragma unroll
        for (int j = 0; j < 8; ++j) {
            float bb = db[h * OO + cg * 8 + j];
            float vq = aq[i][j] + bb;
            float vp = ap[i][j] + bb;
            vq4[j] = vp + (vq - vp);
            float e = vp - vq;
            lsum = fmaf(e, e, lsum);
        }
        float4 s0 = {vq4[0], vq4[1], vq4[2], vq4[3]};
        float4 s1 = {vq4[4], vq4[5], vq4[6], vq4[7]};
        size_t o = (size_t)(b0 + rg * 2 + i) * HIDN + h * OO + cg * 8;
        *(float4*)(out + OUT_ZQ + o) = s0;
        *(float4*)(out + OUT_ZQ + o + 4) = s1;
    }
#pragma unroll
    for (int off = 1; off < 64; off <<= 1) lsum += __shfl_xor(lsum, off);
    if ((t & 63) == 0) redc[t >> 6] = (double)lsum;
    __syncthreads();
    if (t == 0) atomicAdd((double*)(ws + WS_ACC), redc[0] + redc[1] + redc[2] + redc[3]);
}

// ---------------- k6: ortho via LDS hash of co-occurrence pairs ----------------
__global__ __launch_bounds__(256) void k6(float* __restrict__ ws) {
    __shared__ unsigned slots[16384];
    __shared__ unsigned cnts[16384];
    int t = threadIdx.x;
    int bid = blockIdx.x;
    int pi = 0, pj = 1;
    {
        int c = 0;
        for (int a = 0; a < H; ++a)
            for (int b = a + 1; b < H; ++b) { if (c == bid) { pi = a; pj = b; } ++c; }
    }
    for (int s = t; s < 16384; s += 256) { slots[s] = 0xFFFFFFFFu; cnts[s] = 0u; }
    __syncthreads();
    const int* idxi = ((const int*)ws) + WS_IDX;
    for (int b = t; b < BB; b += 256) {
        unsigned key = ((unsigned)idxi[b * H + pi] << 11) | (unsigned)idxi[b * H + pj];
        unsigned p = (key * 2654435761u) >> 18;
        while (true) {
            unsigned old = atomicCAS(&slots[p], 0xFFFFFFFFu, key);
            if (old == 0xFFFFFFFFu || old == key) { atomicAdd(&cnts[p], 1u); break; }
            p = (p + 1) & 16383u;
        }
    }
    __syncthreads();
    const unsigned* hist = ((const unsigned*)ws) + WS_HIST;
    double loc = 0.0;
    for (int s = t; s < 16384; s += 256) {
        unsigned key = slots[s];
        if (key != 0xFFFFFFFFu) {
            int ki = (int)(key >> 11), kj = (int)(key & 2047u);
            float c = (float)cnts[s] * (1.0f / 8192.0f);
            float piv = (float)hist[pi * KK + ki] * (1.0f / 8192.0f);
            float pjv = (float)hist[pj * KK + kj] * (1.0f / 8192.0f);
            float e = piv * pjv;
            loc += (double)fabsf(c - e) - (double)e;
        }
    }
    double spi = 0.0, spj = 0.0;
    for (int k = t; k < KK; k += 256) {
        spi += (double)hist[pi * KK + k];
        spj += (double)hist[pj * KK + k];
    }
#pragma unroll
    for (int off = 1; off < 64; off <<= 1) {
        loc += __shfl_xor(loc, off);
        spi += __shfl_xor(spi, off);
        spj += __shfl_xor(spj, off);
    }
    __syncthreads();
    double* sc = (double*)cnts;
    if ((t & 63) == 0) { int w = t >> 6; sc[w] = loc; sc[4 + w] = spi; sc[8 + w] = spj; }
    __syncthreads();
    if (t == 0) {
        double L = sc[0] + sc[1] + sc[2] + sc[3];
        double SPI = (sc[4] + sc[5] + sc[6] + sc[7]) / 8192.0;
        double SPJ = (sc[8] + sc[9] + sc[10] + sc[11]) / 8192.0;
        atomicAdd(((double*)(ws + WS_ACC)) + 1, L + SPI * SPJ);
    }
}

// ---------------- k4: entropy_loss + scalar finalize ----------------
__global__ __launch_bounds__(256) void k4(float* __restrict__ out, float* __restrict__ ws) {
    __shared__ double red[256];
    int t = threadIdx.x;
    double tot = 0.0;
    for (int h = 0; h < H; ++h) {
        double s = 0.0;
        for (int k = t; k < KK; k += 256) {
            double a = (double)ws[WS_AVGP + h * KK + k] / 8192.0;
            s += a * log(a + 1e-8);
        }
        tot += s;
    }
    red[t] = tot;
    __syncthreads();
    for (int off = 128; off; off >>= 1) {
        if (t < off) red[t] += red[t + off];
        __syncthreads();
    }
    if (t == 0) {
        double entropy = -red[0] / 8.0;
        out[OUT_ENT] = (float)(1.0 - entropy / log(2048.0));
        double ca = *(const double*)(ws + WS_ACC);
        float cm = (float)(ca / (8192.0 * 1024.0));
        out[OUT_COMMIT] = cm;
        out[OUT_CBL] = cm;
        double oa = *(((const double*)(ws + WS_ACC)) + 1);
        out[OUT_ORTHO] = (float)(oa / (28.0 * 4194304.0));
    }
}

extern "C" void kernel_launch(void* const* d_in, const int* in_sizes, int n_in,
                              void* d_out, int out_size, void* d_ws, size_t ws_size,
                              hipStream_t stream) {
    (void)in_sizes; (void)n_in; (void)out_size; (void)ws_size;
    const float* z   = (const float*)d_in[0];
    const float* w1  = (const float*)d_in[1];
    const float* b1  = (const float*)d_in[2];
    const float* w2  = (const float*)d_in[3];
    const float* b2  = (const float*)d_in[4];
    const float* lng = (const float*)d_in[5];
    const float* lnb = (const float*)d_in[6];
    const float* cb  = (const float*)d_in[7];
    const float* dw  = (const float*)d_in[8];
    const float* db  = (const float*)d_in[9];
    float* out = (float*)d_out;
    float* ws = (float*)d_ws;

    hipMemsetAsync(ws + WS_AVGP, 0, WS_ZERO_BYTES, stream);
    k_pre_all<<<328, 256, 0, stream>>>(w1, w2, cb, out, ws);
    k1<<<dim3(32, 8), 1024, 0, stream>>>(z, b1, b2, lng, lnb, out, ws);
    k2<<<dim3(256, 8), 1024, 0, stream>>>(cb, out, ws);
    k3<<<dim3(256, 8), 256, 0, stream>>>(cb, dw, db, out, ws);
    k6<<<28, 256, 0, stream>>>(ws);
    k4<<<1, 256, 0, stream>>>(out, ws);
}

// Round 20
// 514.992 us; speedup vs baseline: 1.1421x; 1.1421x over previous
//
#include <hip/hip_runtime.h>
#include <math.h>

#define H 8
#define KK 2048
#define DD 64
#define HIDN 1024
#define BB 8192
#define TWO_D 128
#define OO 128

// ws float-element offsets
// [0, 1048576): staged codebook fragments — hi-only bf16, chunk-major:
//   tile T stored at slot (T&15)*8 + (T>>4); chunk c sub-slot kg = tile kg*16+c (k = kg*256+c*16+lane)
#define WS_CSQ   1048576
#define WS_ZSQ   1064960
#define WS_IDX   1130496
#define WS_AVGP  1196032
#define WS_HIST  1212416
#define WS_ACC   1228800
#define WS_ZERO_BYTES ((16384 + 16384 + 4) * 4)

#define OUT_ZQ 0
#define OUT_IDX 8388608
#define OUT_COMMIT 8454144
#define OUT_CBL 8454145
#define OUT_ENT 8454146
#define OUT_ORTHO 8454147
#define OUT_ZH 8454148
#define W2P_OFF 3145728

typedef __attribute__((ext_vector_type(8))) short bf16x8;
typedef __attribute__((ext_vector_type(4))) float f32x4;

__device__ inline unsigned short bf16_rne(float x) {
    union { float f; unsigned u; } c; c.f = x;
    unsigned r = c.u + 0x7FFFu + ((c.u >> 16) & 1u);
    return (unsigned short)(r >> 16);
}
__device__ inline float bf16_f32(unsigned short h) {
    union { unsigned u; float f; } c; c.u = ((unsigned)h) << 16;
    return c.f;
}
__device__ inline void split3(float x, short* hh, short* mm, short* ll) {
    unsigned short h_ = bf16_rne(x);
    float r1 = x - bf16_f32(h_);
    unsigned short m_ = bf16_rne(r1);
    float r2 = r1 - bf16_f32(m_);
    unsigned short l_ = bf16_rne(r2);
    *hh = (short)h_; *mm = (short)m_; *ll = (short)l_;
}

__device__ inline void gload_lds16(const void* g, void* l) {
    __builtin_amdgcn_global_load_lds(
        (const __attribute__((address_space(1))) unsigned int*)g,
        (__attribute__((address_space(3))) unsigned int*)l, 16, 0, 0);
}

// ---------------- k_pre_all: w1 pack (0..255) | w2 pack (256..263) | codebook pack (264..327) ----------------
__global__ __launch_bounds__(256) void k_pre_all(const float* __restrict__ w1, const float* __restrict__ w2,
                                                 const float* __restrict__ cb, float* outp,
                                                 float* __restrict__ ws) {
    int bid = blockIdx.x;
    int t = threadIdx.x;
    int l = t & 63, w = t >> 6;
    int lb = l & 15, lg = l >> 4;
    if (bid < 256) {
        short* w1p = (short*)outp;
        int h = bid >> 5, kc = bid & 31;
#pragma unroll
        for (int oi = 0; oi < 2; ++oi) {
            int ot = w + oi * 4;
            union { short e[8]; bf16x8 v; } uh, um, ul;
#pragma unroll
            for (int j = 0; j < 8; ++j) {
                float x = w1[(size_t)(h * HIDN + kc * 32 + lg * 8 + j) * TWO_D + ot * 16 + lb];
                split3(x, &uh.e[j], &um.e[j], &ul.e[j]);
            }
            size_t base = (((size_t)(h * 32 + kc) * 8 + ot) * 3) * 512 + l * 8;
            *(bf16x8*)(w1p + base) = uh.v;
            *(bf16x8*)(w1p + base + 512) = um.v;
            *(bf16x8*)(w1p + base + 1024) = ul.v;
        }
    } else if (bid < 264) {
        short* w2p = (short*)outp + W2P_OFF;
        int h = bid - 256;
#pragma unroll
        for (int i = 0; i < 4; ++i) {
            int fr = w * 4 + i;
            int dt = fr >> 2, oc = fr & 3;
            union { short e[8]; bf16x8 v; } uh, um, ul;
#pragma unroll
            for (int j = 0; j < 8; ++j) {
                float x = w2[(size_t)(h * TWO_D + oc * 32 + lg * 8 + j) * DD + dt * 16 + lb];
                split3(x, &uh.e[j], &um.e[j], &ul.e[j]);
            }
            size_t base = (((size_t)(h * 4 + dt) * 4 + oc) * 3) * 512 + l * 8;
            *(bf16x8*)(w2p + base) = uh.v;
            *(bf16x8*)(w2p + base + 512) = um.v;
            *(bf16x8*)(w2p + base + 1024) = ul.v;
        }
    } else {
        int pb = bid - 264;
        int h = pb >> 3, kb = pb & 7;
        short* stg = (short*)ws;
#pragma unroll
        for (int p = 0; p < 4; ++p) {
            int T = kb * 16 + p * 4 + (t >> 6);
            int k = T * 16 + lb;
            const float* row = cb + (size_t)(h * KK + k) * DD;
            float4 a0 = *(const float4*)(row + ((t >> 4) & 3) * 8);
            float4 a1 = *(const float4*)(row + ((t >> 4) & 3) * 8 + 4);
            float4 c0 = *(const float4*)(row + 32 + ((t >> 4) & 3) * 8);
            float4 c1 = *(const float4*)(row + 32 + ((t >> 4) & 3) * 8 + 4);
            float v0[8] = {a0.x, a0.y, a0.z, a0.w, a1.x, a1.y, a1.z, a1.w};
            float v1[8] = {c0.x, c0.y, c0.z, c0.w, c1.x, c1.y, c1.z, c1.w};
            union { short e[8]; bf16x8 v; } h0, h1;
            float s = 0.f;
#pragma unroll
            for (int j = 0; j < 8; ++j) {
                float x = v0[j];
                s = fmaf(x, x, s);
                h0.e[j] = (short)bf16_rne(x);
                float y = v1[j];
                s = fmaf(y, y, s);
                h1.e[j] = (short)bf16_rne(y);
            }
            int off = (T & 15) * 8 + (T >> 4);
            size_t base = ((size_t)(h * 128 + off)) * 1024 + (t & 63) * 8;
            *(bf16x8*)(stg + base) = h0.v;
            *(bf16x8*)(stg + base + 512) = h1.v;
            s += __shfl_xor(s, 16);
            s += __shfl_xor(s, 32);
            if (((t >> 4) & 3) == 0) ws[WS_CSQ + h * KK + k] = s;
        }
    }
}

// ---------------- k1: MFMA split-3 MLP, 128 rows/block (true r17: each wave = 16 rows x ALL cols) ----------------
__global__ __launch_bounds__(512, 4) void k1(const float* __restrict__ z, const float* __restrict__ b1,
                                             const float* __restrict__ b2, const float* __restrict__ lng,
                                             const float* __restrict__ lnb, float* out,
                                             float* __restrict__ ws) {
    __shared__ char SM[69632];  // [0,49152): 2x24KB staging; epi: h1W 8x[16][68] @0, zhL [128][68] @34816
    int t = threadIdx.x;
    int h = blockIdx.y;
    int b0 = blockIdx.x * 128;
    int w = t >> 6, l = t & 63;
    int lb = l & 15, lg = l >> 4;

    const short* w2p = (const short*)out + W2P_OFF;
    const char* w1h = (const char*)out + (size_t)h * (32 * 24576);
    const float* zrow = z + (size_t)(b0 + w * 16 + lb) * HIDN + lg * 8;

    {
        char* lb0 = SM + (t >> 6) * 1024;
        const char* gb = w1h + t * 16;
#pragma unroll
        for (int r = 0; r < 3; ++r) gload_lds16(gb + r * 8192, lb0 + r * 8192);
#pragma unroll
        for (int r = 0; r < 3; ++r) gload_lds16(gb + 24576 + r * 8192, lb0 + 24576 + r * 8192);
    }
    float4 zA = *(const float4*)(zrow);
    float4 zB = *(const float4*)(zrow + 4);
    __syncthreads();

    f32x4 acc[8];
#pragma unroll
    for (int i = 0; i < 8; ++i) acc[i] = (f32x4){0.f, 0.f, 0.f, 0.f};

#pragma unroll
    for (int c = 0; c < 32; ++c) {
        if (c > 0) {
            if (c < 31) asm volatile("s_waitcnt vmcnt(3)" ::: "memory");
            else        asm volatile("s_waitcnt vmcnt(0)" ::: "memory");
            __builtin_amdgcn_sched_barrier(0);
            __builtin_amdgcn_s_barrier();
            __builtin_amdgcn_sched_barrier(0);
        }
        {
            float zc[8] = {zA.x, zA.y, zA.z, zA.w, zB.x, zB.y, zB.z, zB.w};
            union { short e[8]; bf16x8 v; } uh, um, ul;
#pragma unroll
            for (int j = 0; j < 8; ++j) split3(zc[j], &uh.e[j], &um.e[j], &ul.e[j]);
            bf16x8 bh = uh.v, bm = um.v, blo = ul.v;
            const char* bp = SM + (c & 1) * 24576;
#pragma unroll
            for (int ot = 0; ot < 8; ++ot) {
                const char* fb = bp + ot * 3072 + l * 16;
                bf16x8 ah = *(const bf16x8*)(fb);
                bf16x8 am = *(const bf16x8*)(fb + 1024);
                bf16x8 al = *(const bf16x8*)(fb + 2048);
                f32x4 cc = acc[ot];
                cc = __builtin_amdgcn_mfma_f32_16x16x32_bf16(ah, bh, cc, 0, 0, 0);
                cc = __builtin_amdgcn_mfma_f32_16x16x32_bf16(ah, bm, cc, 0, 0, 0);
                cc = __builtin_amdgcn_mfma_f32_16x16x32_bf16(am, bh, cc, 0, 0, 0);
                cc = __builtin_amdgcn_mfma_f32_16x16x32_bf16(ah, blo, cc, 0, 0, 0);
                cc = __builtin_amdgcn_mfma_f32_16x16x32_bf16(al, bh, cc, 0, 0, 0);
                cc = __builtin_amdgcn_mfma_f32_16x16x32_bf16(am, bm, cc, 0, 0, 0);
                acc[ot] = cc;
            }
        }
        __builtin_amdgcn_sched_barrier(0);
        __builtin_amdgcn_s_barrier();
        __builtin_amdgcn_sched_barrier(0);
        if (c < 31) {
            zA = *(const float4*)(zrow + (c + 1) * 32);
            zB = *(const float4*)(zrow + (c + 1) * 32 + 4);
        }
        if (c + 2 < 32) {
            char* lb0 = SM + (c & 1) * 24576 + (t >> 6) * 1024;
            const char* gb = w1h + (size_t)(c + 2) * 24576 + t * 16;
#pragma unroll
            for (int r = 0; r < 3; ++r) gload_lds16(gb + r * 8192, lb0 + r * 8192);
        }
    }
    __syncthreads();   // staging region dead

    float* h1W = (float*)SM + w * (16 * 68);    // wave-private [16][68]
    float* zhL = (float*)(SM + 34816);          // [128][68]

    f32x4 a2[4];
#pragma unroll
    for (int i = 0; i < 4; ++i) a2[i] = (f32x4){0.f, 0.f, 0.f, 0.f};

#pragma unroll
    for (int half = 0; half < 2; ++half) {
#pragma unroll
        for (int oti = 0; oti < 4; ++oti) {
            int ot = half * 4 + oti;
#pragma unroll
            for (int r = 0; r < 4; ++r) {
                int o = ot * 16 + lg * 4 + r;
                float x = acc[ot][r] + b1[h * TWO_D + o];
                float gl = 0.5f * x * (1.0f + erff(x * 0.70710678118654752f));
                h1W[lb * 68 + (o - half * 64)] = gl;
            }
        }
        __syncthreads();
#pragma unroll
        for (int oci = 0; oci < 2; ++oci) {
            int oc = half * 2 + oci;
            const float* hr = h1W + lb * 68 + oci * 32 + lg * 8;
            union { short e[8]; bf16x8 v; } uh, um, ul;
#pragma unroll
            for (int j = 0; j < 8; ++j) split3(hr[j], &uh.e[j], &um.e[j], &ul.e[j]);
            bf16x8 bh = uh.v, bm = um.v, blo = ul.v;
#pragma unroll
            for (int dt = 0; dt < 4; ++dt) {
                const short* fb = w2p + (((size_t)(h * 4 + dt) * 4 + oc) * 3) * 512 + l * 8;
                bf16x8 ah = *(const bf16x8*)(fb);
                bf16x8 am = *(const bf16x8*)(fb + 512);
                bf16x8 al = *(const bf16x8*)(fb + 1024);
                f32x4 cc = a2[dt];
                cc = __builtin_amdgcn_mfma_f32_16x16x32_bf16(ah, bh, cc, 0, 0, 0);
                cc = __builtin_amdgcn_mfma_f32_16x16x32_bf16(ah, bm, cc, 0, 0, 0);
                cc = __builtin_amdgcn_mfma_f32_16x16x32_bf16(am, bh, cc, 0, 0, 0);
                cc = __builtin_amdgcn_mfma_f32_16x16x32_bf16(ah, blo, cc, 0, 0, 0);
                cc = __builtin_amdgcn_mfma_f32_16x16x32_bf16(al, bh, cc, 0, 0, 0);
                cc = __builtin_amdgcn_mfma_f32_16x16x32_bf16(am, bm, cc, 0, 0, 0);
                a2[dt] = cc;
            }
        }
        __syncthreads();
    }

#pragma unroll
    for (int dt = 0; dt < 4; ++dt)
#pragma unroll
        for (int r = 0; r < 4; ++r) {
            int d = dt * 16 + lg * 4 + r;
            zhL[(w * 16 + lb) * 68 + d] = a2[dt][r] + b2[h * DD + d];
        }
    __syncthreads();

    {
        int row = t >> 2, c0 = (t & 3) * 16;
        const float* zr = zhL + row * 68 + c0;
        float v[16];
#pragma unroll
        for (int j = 0; j < 16; ++j) v[j] = zr[j];
        float s = 0.f;
#pragma unroll
        for (int j = 0; j < 16; ++j) s += v[j];
        s += __shfl_xor(s, 1); s += __shfl_xor(s, 2);
        float mu = s * (1.0f / 64.0f);
        float vv = 0.f;
#pragma unroll
        for (int j = 0; j < 16; ++j) { float d = v[j] - mu; vv = fmaf(d, d, vv); }
        vv += __shfl_xor(vv, 1); vv += __shfl_xor(vv, 2);
        float rstd = 1.0f / sqrtf(vv * (1.0f / 64.0f) + 1e-5f);
        float zn[16]; float ss = 0.f;
#pragma unroll
        for (int j = 0; j < 16; ++j) {
            float x = (v[j] - mu) * rstd * lng[h * DD + c0 + j] + lnb[h * DD + c0 + j];
            zn[j] = x; ss = fmaf(x, x, ss);
        }
        ss += __shfl_xor(ss, 1); ss += __shfl_xor(ss, 2);
        int brow = b0 + row;
        if ((t & 3) == 0) ws[WS_ZSQ + brow * H + h] = ss;
#pragma unroll
        for (int q = 0; q < 4; ++q) {
            float4 sv = {zn[q * 4 + 0], zn[q * 4 + 1], zn[q * 4 + 2], zn[q * 4 + 3]};
            *(float4*)(out + OUT_ZH + (size_t)(brow * H + h) * DD + c0 + q * 4) = sv;
        }
    }
}

// ---------------- k2: hi-only MFMA, 1024-thr / 16-wave blocks (r17; k = kg*256+ai*16+lb) ----------------
#define MARGIN 0.10f
__device__ inline void stage16k(const char* gsrc, short* lbuf, int t) {
    char* lb_ = (char*)lbuf + (t >> 6) * 1024;
    const char* gb = gsrc + t * 16;
    gload_lds16(gb, lb_);
}
__global__ __launch_bounds__(1024) void k2(const float* __restrict__ cb,
                                           float* __restrict__ out, float* __restrict__ ws) {
    __shared__ short bufs[3][8192];
    __shared__ float zt[32][68];
    __shared__ float redM[8][32], redS[8][32], redE[8][32];
    __shared__ int   redK[8][32];
    __shared__ float MbL[32], SbL[32];
    __shared__ float zsqL[32];

    int t = threadIdx.x;
    int h = blockIdx.y;
    int b0 = blockIdx.x * 32;
    int w = t >> 6, l = t & 63;
    int rg = w >> 3, kg = w & 7;
    int lb = l & 15, lg = l >> 4;
    int rmy = rg * 16 + lb;

    const char* stgbase = (const char*)ws + (size_t)h * 262144;

    stage16k(stgbase, bufs[0], t);
    stage16k(stgbase + 16384, bufs[1], t);
    stage16k(stgbase + 32768, bufs[2], t);
#pragma unroll
    for (int i = 0; i < 2; ++i) {
        int q = t + i * 1024;
        int r = q >> 6, d = q & 63;
        zt[r][d] = out[OUT_ZH + (size_t)((b0 + r) * H + h) * DD + d];
    }
    if (t < 32) zsqL[t] = ws[WS_ZSQ + (b0 + t) * H + h];
    __syncthreads();

    bf16x8 bh[2], blo[2];
#pragma unroll
    for (int s = 0; s < 2; ++s) {
        const float* zr = &zt[rmy][s * 32 + lg * 8];
        union { short e[8]; bf16x8 v; } uh, ul;
#pragma unroll
        for (int j = 0; j < 8; ++j) {
            float x = zr[j];
            unsigned short hb = bf16_rne(x);
            uh.e[j] = (short)hb;
            ul.e[j] = (short)bf16_rne(x - bf16_f32(hb));
        }
        bh[s] = uh.v; blo[s] = ul.v;
    }

    f32x4 acc[16];
#pragma unroll
    for (int a = 0; a < 16; ++a) acc[a] = (f32x4){0.f, 0.f, 0.f, 0.f};

#pragma unroll
    for (int c = 0; c < 16; ++c) {
        if (c > 0) {
            if (c <= 13)      asm volatile("s_waitcnt vmcnt(2)" ::: "memory");
            else if (c == 14) asm volatile("s_waitcnt vmcnt(1)" ::: "memory");
            else              asm volatile("s_waitcnt vmcnt(0)" ::: "memory");
            __builtin_amdgcn_sched_barrier(0);
            __builtin_amdgcn_s_barrier();
            __builtin_amdgcn_sched_barrier(0);
        }
        {
            const short* fb = bufs[c % 3] + kg * 1024 + l * 8;
            bf16x8 C0 = *(const bf16x8*)(fb);
            bf16x8 C1 = *(const bf16x8*)(fb + 512);
            f32x4 cc = acc[c];
            cc = __builtin_amdgcn_mfma_f32_16x16x32_bf16(bh[0], C0, cc, 0, 0, 0);
            cc = __builtin_amdgcn_mfma_f32_16x16x32_bf16(blo[0], C0, cc, 0, 0, 0);
            cc = __builtin_amdgcn_mfma_f32_16x16x32_bf16(bh[1], C1, cc, 0, 0, 0);
            cc = __builtin_amdgcn_mfma_f32_16x16x32_bf16(blo[1], C1, cc, 0, 0, 0);
            acc[c] = cc;
        }
        if (c < 15) {
            __builtin_amdgcn_sched_barrier(0);
            __builtin_amdgcn_s_barrier();
            __builtin_amdgcn_sched_barrier(0);
            if (c + 3 < 16)
                stage16k(stgbase + (size_t)(c + 3) * 16384, bufs[c % 3], t);
        }
    }

    float zsqv[4];
#pragma unroll
    for (int r = 0; r < 4; ++r) zsqv[r] = zsqL[rg * 16 + lg * 4 + r];
    float mn[4] = {3.4e38f, 3.4e38f, 3.4e38f, 3.4e38f};
#pragma unroll
    for (int ai = 0; ai < 16; ++ai) {
        float cs = ws[WS_CSQ + h * KK + kg * 256 + ai * 16 + lb];
        f32x4 a = acc[ai];
        f32x4 d;
#pragma unroll
        for (int r = 0; r < 4; ++r) {
            float dv = (zsqv[r] + cs) - 2.f * a[r];
            d[r] = dv;
            mn[r] = fminf(mn[r], dv);
        }
        acc[ai] = d;
    }
#pragma unroll
    for (int off = 1; off < 16; off <<= 1)
#pragma unroll
        for (int r = 0; r < 4; ++r) mn[r] = fminf(mn[r], __shfl_xor(mn[r], off));
    if (lb == 0)
#pragma unroll
        for (int r = 0; r < 4; ++r) redM[kg][rg * 16 + lg * 4 + r] = mn[r];
    __syncthreads();
    if (t < 32) {
        float m = redM[0][t];
#pragma unroll
        for (int g = 1; g < 8; ++g) m = fminf(m, redM[g][t]);
        MbL[t] = m;
    }
    __syncthreads();
    float Mb[4];
#pragma unroll
    for (int r = 0; r < 4; ++r) Mb[r] = MbL[rg * 16 + lg * 4 + r];

    float S[4] = {0.f, 0.f, 0.f, 0.f};
    unsigned mk0 = 0, mk1 = 0, mk2 = 0, mk3 = 0;
#pragma unroll
    for (int ai = 0; ai < 16; ++ai) {
        f32x4 d = acc[ai];
        f32x4 e;
#pragma unroll
        for (int r = 0; r < 4; ++r) {
            float dv = d[r];
            float ev = __expf(Mb[r] - dv);
            S[r] += ev;
            e[r] = ev;
            bool cand = dv <= Mb[r] + MARGIN;
            if (r == 0) mk0 |= cand ? (1u << ai) : 0u;
            if (r == 1) mk1 |= cand ? (1u << ai) : 0u;
            if (r == 2) mk2 |= cand ? (1u << ai) : 0u;
            if (r == 3) mk3 |= cand ? (1u << ai) : 0u;
        }
        acc[ai] = e;
    }
#pragma unroll
    for (int off = 1; off < 16; off <<= 1)
#pragma unroll
        for (int r = 0; r < 4; ++r) S[r] += __shfl_xor(S[r], off);
    if (lb == 0)
#pragma unroll
        for (int r = 0; r < 4; ++r) redS[kg][rg * 16 + lg * 4 + r] = S[r];

    float eB[4] = {3.4e38f, 3.4e38f, 3.4e38f, 3.4e38f};
    int kB[4] = {0x7FFFFFFF, 0x7FFFFFFF, 0x7FFFFFFF, 0x7FFFFFFF};
#pragma unroll
    for (int r = 0; r < 4; ++r) {
        unsigned m = (r == 0) ? mk0 : (r == 1) ? mk1 : (r == 2) ? mk2 : mk3;
        const float* zr0 = &zt[rg * 16 + lg * 4 + r][0];
        float eBest = 3.4e38f; int kBest = 0x7FFFFFFF;
        while (m) {
            int ai = (int)__ffs(m) - 1;
            m &= m - 1;
            int k = kg * 256 + ai * 16 + lb;
            const float4* crow = (const float4*)(cb + (size_t)(h * KK + k) * DD);
            float s = 0.f;
#pragma unroll 1
            for (int q = 0; q < 16; ++q) {
                float4 cv = crow[q];
                s = fmaf(zr0[q * 4 + 0], cv.x, s);
                s = fmaf(zr0[q * 4 + 1], cv.y, s);
                s = fmaf(zr0[q * 4 + 2], cv.z, s);
                s = fmaf(zr0[q * 4 + 3], cv.w, s);
            }
            float ex = (zsqv[r] + ws[WS_CSQ + h * KK + k]) - 2.f * s;
            if (ex < eBest || (ex == eBest && k < kBest)) { eBest = ex; kBest = k; }
        }
        eB[r] = eBest; kB[r] = kBest;
    }
#pragma unroll
    for (int off = 1; off < 16; off <<= 1)
#pragma unroll
        for (int r = 0; r < 4; ++r) {
            float oe = __shfl_xor(eB[r], off);
            int ok = __shfl_xor(kB[r], off);
            if (oe < eB[r] || (oe == eB[r] && ok < kB[r])) { eB[r] = oe; kB[r] = ok; }
        }
    if (lb == 0)
#pragma unroll
        for (int r = 0; r < 4; ++r) {
            redE[kg][rg * 16 + lg * 4 + r] = eB[r];
            redK[kg][rg * 16 + lg * 4 + r] = kB[r];
        }
    __syncthreads();
    if (t < 32) {
        float Sv = redS[0][t];
#pragma unroll
        for (int g = 1; g < 8; ++g) Sv += redS[g][t];
        SbL[t] = Sv;
        float e0 = redE[0][t]; int k0_ = redK[0][t];
#pragma unroll
        for (int g = 1; g < 8; ++g) {
            float oe = redE[g][t]; int ok = redK[g][t];
            if (oe < e0 || (oe == e0 && ok < k0_)) { e0 = oe; k0_ = ok; }
        }
        out[OUT_IDX + (b0 + t) * H + h] = (float)k0_;
        ((int*)ws)[WS_IDX + (b0 + t) * H + h] = k0_;
        atomicAdd(((unsigned*)ws) + WS_HIST + h * KK + k0_, 1u);
    }
    __syncthreads();
    float invS[4];
#pragma unroll
    for (int r = 0; r < 4; ++r) invS[r] = 1.0f / SbL[rg * 16 + lg * 4 + r];

#pragma unroll
    for (int ai = 0; ai < 16; ++ai) {
        f32x4 e = acc[ai];
        float v = e[0] * invS[0];
        v = fmaf(e[1], invS[1], v);
        v = fmaf(e[2], invS[2], v);
        v = fmaf(e[3], invS[3], v);
        v += __shfl_xor(v, 16);
        v += __shfl_xor(v, 32);
        if (lg == 0) atomicAdd(ws + WS_AVGP + h * KK + kg * 256 + ai * 16 + lb, v);
    }
}

// ---------------- k3: decode z_q and z_heads, z_q_st output, commit accum ----------------
__global__ __launch_bounds__(256, 2) void k3(const float* __restrict__ cb, const float* __restrict__ dw,
                                             const float* __restrict__ db, float* __restrict__ out,
                                             float* __restrict__ ws) {
    __shared__ float zqt[32][65];
    __shared__ float zht[32][65];
    __shared__ float dwt[64][128];
    __shared__ int idxs[32];
    __shared__ double redc[4];
    int t = threadIdx.x;
    int h = blockIdx.y;
    int b0 = blockIdx.x * 32;
    if (t < 32) idxs[t] = ((const int*)ws)[WS_IDX + (b0 + t) * H + h];
    __syncthreads();
#pragma unroll
    for (int p = 0; p < 8; ++p) {
        int q = t + 256 * p;
        int r = q >> 6, d = q & 63;
        zqt[r][d] = cb[(size_t)(h * KK + idxs[r]) * DD + d];
        zht[r][d] = out[OUT_ZH + (size_t)((b0 + r) * H + h) * DD + d];
    }
#pragma unroll
    for (int p = 0; p < 8; ++p) {
        int q = t + 256 * p;
        int r = q >> 5, c4 = q & 31;
        *(float4*)(&dwt[r][c4 * 4]) = *(const float4*)(dw + (size_t)(h * DD + r) * OO + c4 * 4);
    }
    __syncthreads();
    int rg = t >> 4, cg = t & 15;
    float aq[2][8], ap[2][8];
#pragma unroll
    for (int i = 0; i < 2; ++i)
#pragma unroll
        for (int j = 0; j < 8; ++j) { aq[i][j] = 0.f; ap[i][j] = 0.f; }
#pragma unroll 4
    for (int d = 0; d < 64; ++d) {
        float q0 = zqt[rg * 2][d], q1 = zqt[rg * 2 + 1][d];
        float p0 = zht[rg * 2][d], p1 = zht[rg * 2 + 1][d];
        float4 wa = *(const float4*)(&dwt[d][cg * 8]);
        float4 wb = *(const float4*)(&dwt[d][cg * 8 + 4]);
        float ww[8] = {wa.x, wa.y, wa.z, wa.w, wb.x, wb.y, wb.z, wb.w};
#pragma unroll
        for (int j = 0; j < 8; ++j) {
            aq[0][j] = fmaf(q0, ww[j], aq[0][j]);
            aq[1][j] = fmaf(q1, ww[j], aq[1][j]);
            ap[0][j] = fmaf(p0, ww[j], ap[0][j]);
            ap[1][j] = fmaf(p1, ww[j], ap[1][j]);
        }
    }
    float lsum = 0.f;
#pragma unroll
    for (int i = 0; i < 2; ++i) {
        float vq4[8];
#pragma unroll
        for (int j = 0; j < 8; ++j) {
            float bb = db[h * OO + cg * 8 + j];
            float vq = aq[i][j] + bb;
            float vp = ap[i][j] + bb;
            vq4[j] = vp + (vq - vp);
            float e = vp - vq;
            lsum = fmaf(e, e, lsum);
        }
        float4 s0 = {vq4[0], vq4[1], vq4[2], vq4[3]};
        float4 s1 = {vq4[4], vq4[5], vq4[6], vq4[7]};
        size_t o = (size_t)(b0 + rg * 2 + i) * HIDN + h * OO + cg * 8;
        *(float4*)(out + OUT_ZQ + o) = s0;
        *(float4*)(out + OUT_ZQ + o + 4) = s1;
    }
#pragma unroll
    for (int off = 1; off < 64; off <<= 1) lsum += __shfl_xor(lsum, off);
    if ((t & 63) == 0) redc[t >> 6] = (double)lsum;
    __syncthreads();
    if (t == 0) atomicAdd((double*)(ws + WS_ACC), redc[0] + redc[1] + redc[2] + redc[3]);
}

// ---------------- k6: ortho via LDS hash of co-occurrence pairs ----------------
__global__ __launch_bounds__(256) void k6(float* __restrict__ ws) {
    __shared__ unsigned slots[16384];
    __shared__ unsigned cnts[16384];
    int t = threadIdx.x;
    int bid = blockIdx.x;
    int pi = 0, pj = 1;
    {
        int c = 0;
        for (int a = 0; a < H; ++a)
            for (int b = a + 1; b < H; ++b) { if (c == bid) { pi = a; pj = b; } ++c; }
    }
    for (int s = t; s < 16384; s += 256) { slots[s] = 0xFFFFFFFFu; cnts[s] = 0u; }
    __syncthreads();
    const int* idxi = ((const int*)ws) + WS_IDX;
    for (int b = t; b < BB; b += 256) {
        unsigned key = ((unsigned)idxi[b * H + pi] << 11) | (unsigned)idxi[b * H + pj];
        unsigned p = (key * 2654435761u) >> 18;
        while (true) {
            unsigned old = atomicCAS(&slots[p], 0xFFFFFFFFu, key);
            if (old == 0xFFFFFFFFu || old == key) { atomicAdd(&cnts[p], 1u); break; }
            p = (p + 1) & 16383u;
        }
    }
    __syncthreads();
    const unsigned* hist = ((const unsigned*)ws) + WS_HIST;
    double loc = 0.0;
    for (int s = t; s < 16384; s += 256) {
        unsigned key = slots[s];
        if (key != 0xFFFFFFFFu) {
            int ki = (int)(key >> 11), kj = (int)(key & 2047u);
            float c = (float)cnts[s] * (1.0f / 8192.0f);
            float piv = (float)hist[pi * KK + ki] * (1.0f / 8192.0f);
            float pjv = (float)hist[pj * KK + kj] * (1.0f / 8192.0f);
            float e = piv * pjv;
            loc += (double)fabsf(c - e) - (double)e;
        }
    }
    double spi = 0.0, spj = 0.0;
    for (int k = t; k < KK; k += 256) {
        spi += (double)hist[pi * KK + k];
        spj += (double)hist[pj * KK + k];
    }
#pragma unroll
    for (int off = 1; off < 64; off <<= 1) {
        loc += __shfl_xor(loc, off);
        spi += __shfl_xor(spi, off);
        spj += __shfl_xor(spj, off);
    }
    __syncthreads();
    double* sc = (double*)cnts;
    if ((t & 63) == 0) { int w = t >> 6; sc[w] = loc; sc[4 + w] = spi; sc[8 + w] = spj; }
    __syncthreads();
    if (t == 0) {
        double L = sc[0] + sc[1] + sc[2] + sc[3];
        double SPI = (sc[4] + sc[5] + sc[6] + sc[7]) / 8192.0;
        double SPJ = (sc[8] + sc[9] + sc[10] + sc[11]) / 8192.0;
        atomicAdd(((double*)(ws + WS_ACC)) + 1, L + SPI * SPJ);
    }
}

// ---------------- k4: entropy_loss + scalar finalize ----------------
__global__ __launch_bounds__(256) void k4(float* __restrict__ out, float* __restrict__ ws) {
    __shared__ double red[256];
    int t = threadIdx.x;
    double tot = 0.0;
    for (int h = 0; h < H; ++h) {
        double s = 0.0;
        for (int k = t; k < KK; k += 256) {
            double a = (double)ws[WS_AVGP + h * KK + k] / 8192.0;
            s += a * log(a + 1e-8);
        }
        tot += s;
    }
    red[t] = tot;
    __syncthreads();
    for (int off = 128; off; off >>= 1) {
        if (t < off) red[t] += red[t + off];
        __syncthreads();
    }
    if (t == 0) {
        double entropy = -red[0] / 8.0;
        out[OUT_ENT] = (float)(1.0 - entropy / log(2048.0));
        double ca = *(const double*)(ws + WS_ACC);
        float cm = (float)(ca / (8192.0 * 1024.0));
        out[OUT_COMMIT] = cm;
        out[OUT_CBL] = cm;
        double oa = *(((const double*)(ws + WS_ACC)) + 1);
        out[OUT_ORTHO] = (float)(oa / (28.0 * 4194304.0));
    }
}

extern "C" void kernel_launch(void* const* d_in, const int* in_sizes, int n_in,
                              void* d_out, int out_size, void* d_ws, size_t ws_size,
                              hipStream_t stream) {
    (void)in_sizes; (void)n_in; (void)out_size; (void)ws_size;
    const float* z   = (const float*)d_in[0];
    const float* w1  = (const float*)d_in[1];
    const float* b1  = (const float*)d_in[2];
    const float* w2  = (const float*)d_in[3];
    const float* b2  = (const float*)d_in[4];
    const float* lng = (const float*)d_in[5];
    const float* lnb = (const float*)d_in[6];
    const float* cb  = (const float*)d_in[7];
    const float* dw  = (const float*)d_in[8];
    const float* db  = (const float*)d_in[9];
    float* out = (float*)d_out;
    float* ws = (float*)d_ws;

    hipMemsetAsync(ws + WS_AVGP, 0, WS_ZERO_BYTES, stream);
    k_pre_all<<<328, 256, 0, stream>>>(w1, w2, cb, out, ws);
    k1<<<dim3(64, 8), 512, 0, stream>>>(z, b1, b2, lng, lnb, out, ws);
    k2<<<dim3(256, 8), 1024, 0, stream>>>(cb, out, ws);
    k3<<<dim3(256, 8), 256, 0, stream>>>(cb, dw, db, out, ws);
    k6<<<28, 256, 0, stream>>>(ws);
    k4<<<1, 256, 0, stream>>>(out, ws);
}